// Round 8
// baseline (211.573 us; speedup 1.0000x reference)
//
#include <hip/hip_runtime.h>
#include <hip/hip_bf16.h>

constexpr int D  = 4096;
constexpr int Q  = 16;
constexpr int L  = 24;
constexpr int C  = 512;
constexpr int RB = 32;              // rows per block
constexpr int KC = 256;             // k-chunk
constexpr int NCH = D / KC;         // 16
constexpr int FSTRIDE = KC + 4;     // 260 dwords; rows stay 16B-aligned
constexpr float PI_F = 3.14159265358979323846f;

// LDS layout (float offsets)
constexpr int OFF_FEAT0 = 0;
constexpr int SZ_FEAT   = RB * FSTRIDE;            // 8320
constexpr int OFF_FEAT1 = OFF_FEAT0 + SZ_FEAT;
constexpr int OFF_PW0   = OFF_FEAT1 + SZ_FEAT;     // 16640
constexpr int SZ_PW     = Q * FSTRIDE;             // 4160
constexpr int OFF_PW1   = OFF_PW0 + SZ_PW;
constexpr int OFF_TRIG  = OFF_PW1 + SZ_PW;         // 24960
constexpr int SZ_TRIG   = L * Q * 6;               // 2304
constexpr int OFF_QUB   = OFF_TRIG + SZ_TRIG;      // 27264
constexpr int SZ_QUB    = RB * Q;                  // 512
constexpr int LDS_FLOATS = OFF_QUB + SZ_QUB;       // 27776 (~111 KB)
constexpr int OFF_RED   = OFF_FEAT0;               // alias featA: 16*512 <= 8320

typedef const __attribute__((address_space(1))) void* gas_ptr;
typedef __attribute__((address_space(3))) void* las_ptr;

__device__ inline void glds16(const float* g, float* l) {
    // stages 16B/lane: LDS dest = wave-uniform base + lane*16 (m104 semantics)
    __builtin_amdgcn_global_load_lds((gas_ptr)g, (las_ptr)l, 16, 0, 0);
}

__device__ inline void stage_chunk(const float* __restrict__ feat,
                                   const float* __restrict__ pw,
                                   float* lds, int row0, int c, int buf,
                                   int wave, int lane, int B) {
    float* fdst = lds + (buf ? OFF_FEAT1 : OFF_FEAT0);
    float* wdst = lds + (buf ? OFF_PW1 : OFF_PW0);
    const int kbase = c * KC;
    // feat: 32 rows x 256 k; each wave stages rows {w, w+8, w+16, w+24}
    #pragma unroll
    for (int p = 0; p < 4; ++p) {
        const int r = p * 8 + wave;                    // wave-uniform
        int rr = row0 + r; if (rr > B - 1) rr = B - 1; // clamp (uniform)
        glds16(feat + (size_t)rr * D + kbase + lane * 4,
               fdst + r * FSTRIDE);
    }
    // pw: 16 rows x 256 k
    #pragma unroll
    for (int p = 0; p < 2; ++p) {
        const int q = p * 8 + wave;                    // wave-uniform
        glds16(pw + (size_t)q * D + kbase + lane * 4,
               wdst + q * FSTRIDE);
    }
}

// All inputs fp32, OUTPUT FP32 (H2: reference returns fp32; "bf16" in the
// harness label is the comparison mode, not the container). VALU GEMM
// projection (memory-bound), fp32 VQC, direct epilogue.
// B/RB blocks x 512 threads, double-buffered k-chunks via global_load_lds.
__global__ __launch_bounds__(512)
void vqc_fused(const float* __restrict__ feat,
               const float* __restrict__ pw,
               const float* __restrict__ pb,
               const float* __restrict__ vw,
               const float* __restrict__ lw,
               const float* __restrict__ lb,
               float* __restrict__ out, int B)
{
    __shared__ float lds[LDS_FLOATS];

    const int t    = threadIdx.x;
    const int wave = t >> 6;
    const int lane = t & 63;
    const int row0 = blockIdx.x * RB;

    // lane micro-tile: 4 q's x 4 rows x (kh half of the wave's 32-k window)
    const int qg = lane & 3;          // q group: q = qg*4 + jq
    const int rg = (lane >> 2) & 7;   // row group: r = rg*4 + jr
    const int kh = lane >> 5;         // k half within window

    // ---- prologue: stage chunk 0, trig table ----
    stage_chunk(feat, pw, lds, row0, 0, 0, wave, lane, B);
    if (t < L * Q) {
        const float phi = vw[t * 3 + 0], th = vw[t * 3 + 1], om = vw[t * 3 + 2];
        float* tr = lds + OFF_TRIG + t * 6;
        tr[0] = cosf(phi); tr[1] = sinf(phi);
        tr[2] = cosf(th);  tr[3] = sinf(th);
        tr[4] = cosf(om);  tr[5] = sinf(om);
    }
    __syncthreads();

    // ---- K loop: 16 chunks of 256, dbuf ----
    float acc[4][4] = {};   // [jq][jr]
    for (int c = 0; c < NCH; ++c) {
        const int buf = c & 1;
        if (c + 1 < NCH)
            stage_chunk(feat, pw, lds, row0, c + 1, buf ^ 1, wave, lane, B);

        const float* fb = lds + (buf ? OFF_FEAT1 : OFF_FEAT0);
        const float* wb = lds + (buf ? OFF_PW1 : OFF_PW0);
        const int k0w = wave * 32 + kh * 4;   // wave's window + lane half
        #pragma unroll
        for (int ii = 0; ii < 4; ++ii) {
            const int koff = k0w + ii * 8;
            float4 w4[4], f4[4];
            #pragma unroll
            for (int jq = 0; jq < 4; ++jq)
                w4[jq] = *(const float4*)(wb + (qg * 4 + jq) * FSTRIDE + koff);
            #pragma unroll
            for (int jr = 0; jr < 4; ++jr)
                f4[jr] = *(const float4*)(fb + (rg * 4 + jr) * FSTRIDE + koff);
            #pragma unroll
            for (int jq = 0; jq < 4; ++jq)
                #pragma unroll
                for (int jr = 0; jr < 4; ++jr) {
                    acc[jq][jr] = fmaf(w4[jq].x, f4[jr].x, acc[jq][jr]);
                    acc[jq][jr] = fmaf(w4[jq].y, f4[jr].y, acc[jq][jr]);
                    acc[jq][jr] = fmaf(w4[jq].z, f4[jr].z, acc[jq][jr]);
                    acc[jq][jr] = fmaf(w4[jq].w, f4[jr].w, acc[jq][jr]);
                }
        }
        __syncthreads();   // drains async loads; WAR-protects buffers
    }

    // ---- reduce 16 partials (8 waves x 2 kh) per (row, q) via LDS ----
    {
        float* red = lds + OFF_RED;   // aliases featA (free after last chunk)
        const int slot = wave * 2 + kh;
        #pragma unroll
        for (int jq = 0; jq < 4; ++jq)
            #pragma unroll
            for (int jr = 0; jr < 4; ++jr)
                red[slot * 512 + (rg * 4 + jr) * 16 + (qg * 4 + jq)] = acc[jq][jr];
    }
    __syncthreads();

    // ---- VQC: one thread per (row, q), fp32 ----
    {
        const int r = t >> 4, q = t & 15;
        const float* red = lds + OFF_RED;
        float p = 0.f;
        #pragma unroll
        for (int i = 0; i < 16; ++i) p += red[i * 512 + r * 16 + q];
        p += pb[q];
        const float angle = PI_F * tanhf(p);
        float x = sinf(angle), y = 0.f, z = cosf(angle);
        const float* tr = lds + OFF_TRIG;
        #pragma unroll
        for (int l = 0; l < L; ++l) {
            const float* w6 = tr + (l * 16 + q) * 6;
            const float cp = w6[0], sp = w6[1];
            const float ct = w6[2], st = w6[3];
            const float co = w6[4], so = w6[5];
            const float x1 = x * cp - y * sp;
            const float y1 = x * sp + y * cp;
            const float x2 = x1 * ct + z * st;
            const float z2 = -x1 * st + z * ct;
            x = x2 * co - y1 * so;
            y = x2 * so + y1 * co;
            z = z2;
        }
        lds[OFF_QUB + r * 16 + q] = z;
    }
    __syncthreads();

    // ---- epilogue: out[RB][512] = qubits[RB][16] @ lw[16][512] + lb ----
    {
        const int cc = t;   // one output column per thread
        float wv[Q];
        #pragma unroll
        for (int q = 0; q < Q; ++q) wv[q] = lw[(size_t)q * C + cc];
        const float lbv = lb[cc];
        const float* qub = lds + OFF_QUB;
        #pragma unroll 4
        for (int r = 0; r < RB; ++r) {
            if (row0 + r >= B) break;
            float a2 = lbv;
            #pragma unroll
            for (int q = 0; q < Q; ++q) a2 = fmaf(qub[r * 16 + q], wv[q], a2);
            out[(size_t)(row0 + r) * C + cc] = a2;   // fp32 store (H2)
        }
    }
}

extern "C" void kernel_launch(void* const* d_in, const int* in_sizes, int n_in,
                              void* d_out, int out_size, void* d_ws, size_t ws_size,
                              hipStream_t stream) {
    // Size-keyed input mapping (permutation-proof; falls back to dict order).
    const float *feat = nullptr, *pw = nullptr, *pb = nullptr,
                *vw = nullptr, *lw = nullptr, *lb = nullptr;
    long long B = 0;
    bool ok = false;
    if (n_in == 6) {
        int imax = 0;
        for (int i = 1; i < 6; ++i)
            if ((long long)in_sizes[i] > (long long)in_sizes[imax]) imax = i;
        const long long scales[2] = {1, 4};
        for (int s = 0; s < 2 && !ok; ++s) {
            const long long sc = scales[s];
            int m[6] = {imax, -1, -1, -1, -1, -1};
            bool good = ((long long)in_sizes[imax] % (sc * D)) == 0;
            for (int i = 0; i < 6 && good; ++i) {
                if (i == imax) continue;
                long long e = (long long)in_sizes[i];
                if (e % sc) { good = false; break; }
                e /= sc;
                if      (e == 65536 && m[1] < 0) m[1] = i;
                else if (e == 16    && m[2] < 0) m[2] = i;
                else if (e == 1152  && m[3] < 0) m[3] = i;
                else if (e == 8192  && m[4] < 0) m[4] = i;
                else if (e == 512   && m[5] < 0) m[5] = i;
                else good = false;
            }
            if (good && m[1] >= 0 && m[2] >= 0 && m[3] >= 0 && m[4] >= 0 && m[5] >= 0) {
                feat = (const float*)d_in[m[0]];
                pw   = (const float*)d_in[m[1]];
                pb   = (const float*)d_in[m[2]];
                vw   = (const float*)d_in[m[3]];
                lw   = (const float*)d_in[m[4]];
                lb   = (const float*)d_in[m[5]];
                B = (long long)in_sizes[imax] / (sc * D);
                ok = true;
            }
        }
    }
    if (!ok) {   // fallback: setup_inputs dict order, element counts
        feat = (const float*)d_in[0];
        pw   = (const float*)d_in[1];
        pb   = (const float*)d_in[2];
        vw   = (const float*)d_in[3];
        lw   = (const float*)d_in[4];
        lb   = (const float*)d_in[5];
        B = in_sizes[0] / D;
    }
    float* out = (float*)d_out;

    const int nblocks = (int)((B + RB - 1) / RB);
    dim3 grid(nblocks), block(512);
    hipLaunchKernelGGL(vqc_fused, grid, block, 0, stream,
                       feat, pw, pb, vw, lw, lb, out, (int)B);
}

// Round 9
// 206.466 us; speedup vs baseline: 1.0247x; 1.0247x over previous
//
#include <hip/hip_runtime.h>
#include <hip/hip_bf16.h>

using short8  = __attribute__((ext_vector_type(8))) short;
using floatx4 = __attribute__((ext_vector_type(4))) float;

constexpr int D  = 4096;
constexpr int Q  = 16;
constexpr int L  = 24;
constexpr int C  = 512;
constexpr int RB = 16;              // rows per block = one MFMA M-tile
constexpr int NW = 8;               // waves per block
constexpr int KW = D / NW;          // 512 k per wave
constexpr int NSTEP = KW / 32;      // 16 MFMA k-steps per wave
constexpr float PI_F = 3.14159265358979323846f;

// fp32 -> bf16 hi/lo by truncation. hi = top 16 bits (trunc toward zero of
// the mantissa); residual r = f - hi_f is EXACT (same-exponent subtract of
// truncated low bits); lo = trunc(r). Dropped lo*lo term ~2^-24 rel.
__device__ inline void cvt8(const float4& v0, const float4& v1,
                            short8& hi, short8& lo) {
    const float f[8] = {v0.x, v0.y, v0.z, v0.w, v1.x, v1.y, v1.z, v1.w};
    #pragma unroll
    for (int j = 0; j < 8; ++j) {
        union { float f; unsigned u; } a, b, c;
        a.f = f[j];
        hi[j] = (short)(a.u >> 16);
        b.u = a.u & 0xFFFF0000u;
        c.f = a.f - b.f;
        lo[j] = (short)(c.u >> 16);
    }
}

// All inputs fp32, output fp32. Barrier-free K-loop: each of 8 waves owns a
// 512-k slice of the 16-row x 16-q projection via MFMA 16x16x32 bf16 with
// hi/lo split (fragment mapping cross-validated against the passing fp32-VALU
// kernel). No LDS in the hot loop -> 2 blocks/CU, 16 waves/CU, free-running
// HBM stream. LDS only for one-time reduce + VQC + epilogue.
__global__ __launch_bounds__(512, 4)
void vqc_fused(const float* __restrict__ feat,
               const float* __restrict__ pw,
               const float* __restrict__ pb,
               const float* __restrict__ vw,
               const float* __restrict__ lw,
               const float* __restrict__ lb,
               float* __restrict__ out, int B)
{
    __shared__ float s_red[NW][RB][Q];   // 8 KB  per-wave partial proj tiles
    __shared__ float s_trig[L * Q * 6];  // 9 KB  cp,sp,ct,st,co,so
    __shared__ float s_qub[RB][Q];       // 1 KB  VQC z output

    const int t    = threadIdx.x;
    const int wave = t >> 6;
    const int lane = t & 63;
    const int row0 = blockIdx.x * RB;
    const int mrow = lane & 15;          // A row (feat) / B row (q)
    const int quad = lane >> 4;

    // ---- trig table (block-invariant, one-time) ----
    if (t < L * Q) {
        const float phi = vw[t * 3 + 0], th = vw[t * 3 + 1], om = vw[t * 3 + 2];
        float* tr = s_trig + t * 6;
        tr[0] = cosf(phi); tr[1] = sinf(phi);
        tr[2] = cosf(th);  tr[3] = sinf(th);
        tr[4] = cosf(om);  tr[5] = sinf(om);
    }

    // ---- projection K-loop: barrier-free, register-only ----
    int rr = row0 + mrow; if (rr >= B) rr = B - 1;   // clamp; stores guarded
    const float* ap = feat + (size_t)rr * D + wave * KW + quad * 8;
    const float* bp = pw   + (size_t)mrow * D + wave * KW + quad * 8;

    floatx4 acc = {0.f, 0.f, 0.f, 0.f};
    #pragma unroll 4
    for (int s = 0; s < NSTEP; ++s) {
        const float4 a0 = *(const float4*)(ap + s * 32);
        const float4 a1 = *(const float4*)(ap + s * 32 + 4);
        const float4 b0 = *(const float4*)(bp + s * 32);
        const float4 b1 = *(const float4*)(bp + s * 32 + 4);
        short8 ah, al, bh, bl;
        cvt8(a0, a1, ah, al);
        cvt8(b0, b1, bh, bl);
        acc = __builtin_amdgcn_mfma_f32_16x16x32_bf16(al, bh, acc, 0, 0, 0);
        acc = __builtin_amdgcn_mfma_f32_16x16x32_bf16(ah, bl, acc, 0, 0, 0);
        acc = __builtin_amdgcn_mfma_f32_16x16x32_bf16(ah, bh, acc, 0, 0, 0);
    }
    // C/D layout: col (=q) = lane&15, row (=m) = quad*4 + reg
    #pragma unroll
    for (int i = 0; i < 4; ++i)
        s_red[wave][quad * 4 + i][mrow] = acc[i];
    __syncthreads();

    // ---- VQC: one thread per (row, q), fp32 ----
    if (t < RB * Q) {
        const int r = t >> 4, q = t & 15;
        float p = 0.f;
        #pragma unroll
        for (int w = 0; w < NW; ++w) p += s_red[w][r][q];
        p += pb[q];
        const float angle = PI_F * tanhf(p);
        float x = sinf(angle), y = 0.f, z = cosf(angle);
        #pragma unroll
        for (int l = 0; l < L; ++l) {
            const float* w6 = s_trig + (l * 16 + q) * 6;
            const float cp = w6[0], sp = w6[1];
            const float ct = w6[2], st = w6[3];
            const float co = w6[4], so = w6[5];
            const float x1 = x * cp - y * sp;
            const float y1 = x * sp + y * cp;
            const float x2 = x1 * ct + z * st;
            const float z2 = -x1 * st + z * ct;
            x = x2 * co - y1 * so;
            y = x2 * so + y1 * co;
            z = z2;
        }
        s_qub[r][q] = z;
    }
    __syncthreads();

    // ---- epilogue: out[RB][512] = qubits[RB][16] @ lw[16][512] + lb ----
    {
        const int c = t;   // 512 threads -> one output column each
        float wv[Q];
        #pragma unroll
        for (int q = 0; q < Q; ++q) wv[q] = lw[(size_t)q * C + c];
        const float lbv = lb[c];
        #pragma unroll 4
        for (int r = 0; r < RB; ++r) {
            if (row0 + r >= B) break;
            float a2 = lbv;
            #pragma unroll
            for (int q = 0; q < Q; ++q) a2 = fmaf(s_qub[r][q], wv[q], a2);
            out[(size_t)(row0 + r) * C + c] = a2;
        }
    }
}

extern "C" void kernel_launch(void* const* d_in, const int* in_sizes, int n_in,
                              void* d_out, int out_size, void* d_ws, size_t ws_size,
                              hipStream_t stream) {
    // Size-keyed input mapping (permutation-proof; falls back to dict order).
    const float *feat = nullptr, *pw = nullptr, *pb = nullptr,
                *vw = nullptr, *lw = nullptr, *lb = nullptr;
    long long B = 0;
    bool ok = false;
    if (n_in == 6) {
        int imax = 0;
        for (int i = 1; i < 6; ++i)
            if ((long long)in_sizes[i] > (long long)in_sizes[imax]) imax = i;
        const long long scales[2] = {1, 4};
        for (int s = 0; s < 2 && !ok; ++s) {
            const long long sc = scales[s];
            int m[6] = {imax, -1, -1, -1, -1, -1};
            bool good = ((long long)in_sizes[imax] % (sc * D)) == 0;
            for (int i = 0; i < 6 && good; ++i) {
                if (i == imax) continue;
                long long e = (long long)in_sizes[i];
                if (e % sc) { good = false; break; }
                e /= sc;
                if      (e == 65536 && m[1] < 0) m[1] = i;
                else if (e == 16    && m[2] < 0) m[2] = i;
                else if (e == 1152  && m[3] < 0) m[3] = i;
                else if (e == 8192  && m[4] < 0) m[4] = i;
                else if (e == 512   && m[5] < 0) m[5] = i;
                else good = false;
            }
            if (good && m[1] >= 0 && m[2] >= 0 && m[3] >= 0 && m[4] >= 0 && m[5] >= 0) {
                feat = (const float*)d_in[m[0]];
                pw   = (const float*)d_in[m[1]];
                pb   = (const float*)d_in[m[2]];
                vw   = (const float*)d_in[m[3]];
                lw   = (const float*)d_in[m[4]];
                lb   = (const float*)d_in[m[5]];
                B = (long long)in_sizes[imax] / (sc * D);
                ok = true;
            }
        }
    }
    if (!ok) {   // fallback: setup_inputs dict order, element counts
        feat = (const float*)d_in[0];
        pw   = (const float*)d_in[1];
        pb   = (const float*)d_in[2];
        vw   = (const float*)d_in[3];
        lw   = (const float*)d_in[4];
        lb   = (const float*)d_in[5];
        B = in_sizes[0] / D;
    }
    float* out = (float*)d_out;

    const int nblocks = (int)((B + RB - 1) / RB);
    dim3 grid(nblocks), block(512);
    hipLaunchKernelGGL(vqc_fused, grid, block, 0, stream,
                       feat, pw, pb, vw, lw, lb, out, (int)B);
}